// Round 1
// baseline (1939.342 us; speedup 1.0000x reference)
//
#include <hip/hip_runtime.h>
#include <hip/hip_bf16.h>

typedef unsigned short u16;
typedef __bf16 bf16x8 __attribute__((ext_vector_type(8)));
typedef unsigned short u16x8 __attribute__((ext_vector_type(8)));
typedef unsigned short u16x4 __attribute__((ext_vector_type(4)));
typedef float f32x4 __attribute__((ext_vector_type(4)));

#define B_ 8
#define T_ 2048
#define E_ 1024
#define H_ 1024
#define M_ (B_ * T_)   // 16384

__device__ inline u16 f2bf(float f) {
    __bf16 h = (__bf16)f;
    return __builtin_bit_cast(u16, h);
}

__device__ inline bf16x8 load_frag(const u16* p) {
    u16x8 u = *(const u16x8*)p;
    return __builtin_bit_cast(bf16x8, u);
}

// ---------------- cast fp32 -> bf16, 4 elems/thread ----------------
__global__ void castk(const float* __restrict__ in, u16* __restrict__ out, int n) {
    int i = (blockIdx.x * blockDim.x + threadIdx.x) * 4;
    if (i < n) {
        f32x4 f = *(const f32x4*)(in + i);
        u16x4 u;
        u[0] = f2bf(f[0]); u[1] = f2bf(f[1]); u[2] = f2bf(f[2]); u[3] = f2bf(f[3]);
        *(u16x4*)(out + i) = u;
    }
}

// ---------------- GEMM: out[m,n] = sum_k A[m,k] * Bw[n,k]  (B^T layout) ----
// A: [M, K=1024] bf16, Bw: [N=1024, K=1024] bf16.
// transpose_out==0: out bf16 [M, 1024]
// transpose_out==1: out bf16 [B, 1024, 2048]  (v transposed: [b][h][t])
__global__ __launch_bounds__(256) void gemm_bt(const u16* __restrict__ A,
                                               const u16* __restrict__ Bw,
                                               u16* __restrict__ out,
                                               int transpose_out) {
    const int K = E_;
    const int bm = blockIdx.x;          // M/64
    const int bn = blockIdx.y;          // N/64
    const int w = threadIdx.x >> 6;     // wave 0..3
    const int lane = threadIdx.x & 63;
    const int quad = lane >> 4;
    const int l16 = lane & 15;

    const int m = bm * 64 + w * 16 + l16;
    f32x4 acc[4] = {};

    const u16* ap = A + (size_t)m * K + quad * 8;
    const u16* bp = Bw + (size_t)(bn * 64 + l16) * K + quad * 8;

    for (int kk = 0; kk < K; kk += 32) {
        bf16x8 a = load_frag(ap + kk);
#pragma unroll
        for (int c = 0; c < 4; c++) {
            bf16x8 b = load_frag(bp + (size_t)c * 16 * K + kk);
            acc[c] = __builtin_amdgcn_mfma_f32_16x16x32_bf16(a, b, acc[c], 0, 0, 0);
        }
    }

#pragma unroll
    for (int c = 0; c < 4; c++) {
#pragma unroll
        for (int r = 0; r < 4; r++) {
            int row = bm * 64 + w * 16 + quad * 4 + r;  // C/D: row = quad*4+reg
            int col = bn * 64 + c * 16 + l16;           // C/D: col = lane&15
            u16 v = f2bf(acc[c][r]);
            if (!transpose_out) {
                out[(size_t)row * H_ + col] = v;
            } else {
                int b = row >> 11;       // / T_
                int t = row & (T_ - 1);
                out[((size_t)b * H_ + col) * T_ + t] = v;
            }
        }
    }
}

// ---------------- flash attention ----------------
// qb, kb: bf16 [B, T, H]; vtb: bf16 [B, H, T]; out: fp32 [B, T, H]
// One workgroup (4 waves) per (batch, 16-row q-tile).
// Wave w owns output cols [w*256, (w+1)*256): 16 mfma tiles -> o[16] f32x4.
#define SP 65   // LDS stride pad for S/P
__global__ __launch_bounds__(256) void attn(const u16* __restrict__ qb,
                                            const u16* __restrict__ kb,
                                            const u16* __restrict__ vtb,
                                            float* __restrict__ out) {
    const int b = blockIdx.y;
    const int t0 = ((int)gridDim.x - 1 - (int)blockIdx.x) * 16;  // big work first
    const int w = threadIdx.x >> 6;
    const int lane = threadIdx.x & 63;
    const int quad = lane >> 4;
    const int l16 = lane & 15;
    const int srow = threadIdx.x >> 4;  // 0..15 softmax row
    const int sg = threadIdx.x & 15;    // 0..15 softmax col-group

    __shared__ float S[16 * SP];
    __shared__ float m_s[16], l_s[16], a_s[16];

    if (threadIdx.x < 16) {
        m_s[threadIdx.x] = -__builtin_inff();
        l_s[threadIdx.x] = 0.f;
    }
    f32x4 o[16] = {};

    const u16* qB = qb + (size_t)b * T_ * H_;
    const u16* kB = kb + (size_t)b * T_ * H_;
    const u16* vB = vtb + (size_t)b * H_ * T_;
    const float scale = 0.03125f;  // E^-0.5

    __syncthreads();

    for (int s0 = 0; s0 <= t0 + 15; s0 += 64) {
        // ---- 1. S-tile: wave w computes cols [w*16, w*16+16) over full H
        f32x4 sc = {};
        const u16* qp = qB + (size_t)(t0 + l16) * H_ + quad * 8;
        const u16* kp = kB + (size_t)(s0 + w * 16 + l16) * H_ + quad * 8;
        for (int kk = 0; kk < H_; kk += 32) {
            bf16x8 a = load_frag(qp + kk);
            bf16x8 kf = load_frag(kp + kk);
            sc = __builtin_amdgcn_mfma_f32_16x16x32_bf16(a, kf, sc, 0, 0, 0);
        }
        // write to LDS with scale + causal mask
#pragma unroll
        for (int r = 0; r < 4; r++) {
            int row = quad * 4 + r;
            int col = w * 16 + l16;
            int t = t0 + row, s = s0 + col;
            S[row * SP + col] = (s <= t) ? sc[r] * scale : -__builtin_inff();
        }
        __syncthreads();

        // ---- 2. online softmax (16 threads per row)
        float v0 = S[srow * SP + sg];
        float v1 = S[srow * SP + sg + 16];
        float v2 = S[srow * SP + sg + 32];
        float v3 = S[srow * SP + sg + 48];
        float rmax = fmaxf(fmaxf(v0, v1), fmaxf(v2, v3));
#pragma unroll
        for (int off = 8; off >= 1; off >>= 1)
            rmax = fmaxf(rmax, __shfl_xor(rmax, off, 64));
        if (sg == 0) {
            float mo = m_s[srow];
            float mn = fmaxf(mo, rmax);
            m_s[srow] = mn;
            a_s[srow] = (mo == -__builtin_inff()) ? 0.f : __expf(mo - mn);
        }
        __syncthreads();
        float mn = m_s[srow];
        float p0 = (v0 == -__builtin_inff()) ? 0.f : __expf(v0 - mn);
        float p1 = (v1 == -__builtin_inff()) ? 0.f : __expf(v1 - mn);
        float p2 = (v2 == -__builtin_inff()) ? 0.f : __expf(v2 - mn);
        float p3 = (v3 == -__builtin_inff()) ? 0.f : __expf(v3 - mn);
        S[srow * SP + sg] = p0;
        S[srow * SP + sg + 16] = p1;
        S[srow * SP + sg + 32] = p2;
        S[srow * SP + sg + 48] = p3;
        float rsum = p0 + p1 + p2 + p3;
#pragma unroll
        for (int off = 8; off >= 1; off >>= 1)
            rsum += __shfl_xor(rsum, off, 64);
        if (sg == 0)
            l_s[srow] = l_s[srow] * a_s[srow] + rsum;
        __syncthreads();

        // ---- 3. rescale O, then PV
        float al[4];
#pragma unroll
        for (int r = 0; r < 4; r++) al[r] = a_s[quad * 4 + r];
#pragma unroll
        for (int ht = 0; ht < 16; ht++) {
#pragma unroll
            for (int r = 0; r < 4; r++) o[ht][r] *= al[r];
        }
#pragma unroll
        for (int kc = 0; kc < 2; kc++) {
            // P A-fragment: A[m=l16][k=kc*32+quad*8+j] from LDS (fp32 -> bf16)
            bf16x8 pa;
#pragma unroll
            for (int j = 0; j < 8; j++)
                pa[j] = (__bf16)S[l16 * SP + kc * 32 + quad * 8 + j];
            const u16* vp = vB + (size_t)(w * 256 + l16) * T_ + s0 + kc * 32 + quad * 8;
#pragma unroll
            for (int ht = 0; ht < 16; ht++) {
                bf16x8 vf = load_frag(vp + (size_t)ht * 16 * T_);
                o[ht] = __builtin_amdgcn_mfma_f32_16x16x32_bf16(pa, vf, o[ht], 0, 0, 0);
            }
        }
        __syncthreads();
    }

    // ---- epilogue: O / l
    float linv[4];
#pragma unroll
    for (int r = 0; r < 4; r++) linv[r] = 1.f / l_s[quad * 4 + r];
    float* ob = out + (size_t)b * T_ * H_;
#pragma unroll
    for (int ht = 0; ht < 16; ht++) {
        int col = w * 256 + ht * 16 + l16;
#pragma unroll
        for (int r = 0; r < 4; r++) {
            int row = t0 + quad * 4 + r;
            ob[(size_t)row * H_ + col] = o[ht][r] * linv[r];
        }
    }
}

extern "C" void kernel_launch(void* const* d_in, const int* in_sizes, int n_in,
                              void* d_out, int out_size, void* d_ws, size_t ws_size,
                              hipStream_t stream) {
    const float* x  = (const float*)d_in[0];
    const float* Wk = (const float*)d_in[1];
    const float* Wq = (const float*)d_in[2];
    const float* Wv = (const float*)d_in[3];
    float* out = (float*)d_out;

    char* ws = (char*)d_ws;
    const size_t SZ_XB = (size_t)M_ * E_ * 2;       // 33554432
    const size_t SZ_QKV = (size_t)M_ * H_ * 2;      // 33554432
    const size_t SZ_W = (size_t)H_ * E_ * 2;        // 2097152
    u16* xb  = (u16*)(ws);
    u16* qb  = (u16*)(ws + SZ_XB);
    u16* kb  = (u16*)(ws + SZ_XB + SZ_QKV);
    u16* vtb = (u16*)(ws + SZ_XB + 2 * SZ_QKV);
    u16* wqb = (u16*)(ws + SZ_XB + 3 * SZ_QKV);
    u16* wkb = (u16*)(ws + SZ_XB + 3 * SZ_QKV + SZ_W);
    u16* wvb = (u16*)(ws + SZ_XB + 3 * SZ_QKV + 2 * SZ_W);

    castk<<<M_ * E_ / 4 / 256, 256, 0, stream>>>(x, xb, M_ * E_);
    castk<<<H_ * E_ / 4 / 256, 256, 0, stream>>>(Wk, wkb, H_ * E_);
    castk<<<H_ * E_ / 4 / 256, 256, 0, stream>>>(Wq, wqb, H_ * E_);
    castk<<<H_ * E_ / 4 / 256, 256, 0, stream>>>(Wv, wvb, H_ * E_);

    dim3 gg(M_ / 64, H_ / 64);
    gemm_bt<<<gg, 256, 0, stream>>>(xb, wqb, qb, 0);
    gemm_bt<<<gg, 256, 0, stream>>>(xb, wkb, kb, 0);
    gemm_bt<<<gg, 256, 0, stream>>>(xb, wvb, vtb, 1);

    attn<<<dim3(T_ / 16, B_), 256, 0, stream>>>(qb, kb, vtb, out);
}

// Round 2
// 560.676 us; speedup vs baseline: 3.4589x; 3.4589x over previous
//
#include <hip/hip_runtime.h>
#include <hip/hip_bf16.h>

typedef unsigned short u16;
typedef __bf16 bf16x8 __attribute__((ext_vector_type(8)));
typedef unsigned short u16x8 __attribute__((ext_vector_type(8)));
typedef unsigned short u16x4 __attribute__((ext_vector_type(4)));
typedef float f32x4 __attribute__((ext_vector_type(4)));

#define B_ 8
#define T_ 2048
#define E_ 1024
#define H_ 1024
#define M_ (B_ * T_)   // 16384

__device__ inline u16 f2bf(float f) {
    __bf16 h = (__bf16)f;
    return __builtin_bit_cast(u16, h);
}

__device__ inline bf16x8 load_frag(const u16* p) {
    u16x8 u = *(const u16x8*)p;
    return __builtin_bit_cast(bf16x8, u);
}

// async global->LDS, 16 bytes per lane. LDS dest must be wave-uniform-base + lane*16.
__device__ inline void gload_lds16(const u16* g, u16* l) {
    __builtin_amdgcn_global_load_lds(
        (__attribute__((address_space(1))) unsigned int*)(g),
        (__attribute__((address_space(3))) unsigned int*)(l), 16, 0, 0);
}

// ---------------- cast fp32 -> bf16, 4 elems/thread ----------------
__global__ void castk(const float* __restrict__ in, u16* __restrict__ out, int n) {
    int i = (blockIdx.x * blockDim.x + threadIdx.x) * 4;
    if (i < n) {
        f32x4 f = *(const f32x4*)(in + i);
        u16x4 u;
        u[0] = f2bf(f[0]); u[1] = f2bf(f[1]); u[2] = f2bf(f[2]); u[3] = f2bf(f[3]);
        *(u16x4*)(out + i) = u;
    }
}

// ---------------- fused QKV GEMM, m97-style ----------------
// A: [16384][1024] bf16, W: [3072][1024] bf16 ([Wq;Wk;Wv], row-major, K-major)
// out: qo/ko bf16 [M][1024]; vo bf16 [B][1024][2048] (transposed)
// 128x128 tile, BK=64, 4 waves, global_load_lds staging, XOR-swizzled LDS chunks.
__global__ __launch_bounds__(256) void gemm_qkv(const u16* __restrict__ A,
                                                const u16* __restrict__ W,
                                                u16* __restrict__ qo,
                                                u16* __restrict__ ko,
                                                u16* __restrict__ vo) {
    const int bm = blockIdx.x, bn = blockIdx.y;
    const int tid = threadIdx.x;
    const int w = tid >> 6, lane = tid & 63, quad = lane >> 4, l16 = lane & 15;
    const int wr = w & 1, wc = w >> 1;

    __shared__ u16 As[128 * 64];   // 16 KB, 16B chunks: slot = row*8 + (cc ^ (row&7))
    __shared__ u16 Bs[128 * 64];

    f32x4 acc[16] = {};  // acc[ri*4+ci]

    const u16* Ab = A + (size_t)(bm * 128) * E_;
    const u16* Wb = W + (size_t)(bn * 128) * E_;

    for (int kk = 0; kk < E_; kk += 64) {
        __syncthreads();   // prev LDS reads done before restage
#pragma unroll
        for (int i = 0; i < 4; i++) {
            int chunk = i * 256 + tid;       // 0..1023
            int row = chunk >> 3, cc = chunk & 7;
            int ccs = cc ^ (row & 7);        // swizzled global chunk for this slot
            gload_lds16(Ab + (size_t)row * E_ + kk + ccs * 8, &As[chunk * 8]);
            gload_lds16(Wb + (size_t)row * E_ + kk + ccs * 8, &Bs[chunk * 8]);
        }
        __syncthreads();   // staging complete (vmcnt drained by barrier)
#pragma unroll
        for (int k2 = 0; k2 < 2; k2++) {
            bf16x8 af[4], bf[4];
#pragma unroll
            for (int ri = 0; ri < 4; ri++) {
                int m = wr * 64 + ri * 16 + l16;
                int slot = m * 8 + ((k2 * 4 + quad) ^ (m & 7));
                af[ri] = load_frag(&As[slot * 8]);
            }
#pragma unroll
            for (int ci = 0; ci < 4; ci++) {
                int n = wc * 64 + ci * 16 + l16;
                int slot = n * 8 + ((k2 * 4 + quad) ^ (n & 7));
                bf[ci] = load_frag(&Bs[slot * 8]);
            }
#pragma unroll
            for (int ri = 0; ri < 4; ri++)
#pragma unroll
                for (int ci = 0; ci < 4; ci++)
                    acc[ri * 4 + ci] = __builtin_amdgcn_mfma_f32_16x16x32_bf16(
                        af[ri], bf[ci], acc[ri * 4 + ci], 0, 0, 0);
        }
    }

    const int nbase = bn * 128;
#pragma unroll
    for (int ri = 0; ri < 4; ri++) {
#pragma unroll
        for (int ci = 0; ci < 4; ci++) {
#pragma unroll
            for (int r = 0; r < 4; r++) {
                int row = bm * 128 + wr * 64 + ri * 16 + quad * 4 + r;  // C/D row = quad*4+reg
                int n = nbase + wc * 64 + ci * 16 + l16;                // C/D col = lane&15
                u16 v = f2bf(acc[ri * 4 + ci][r]);
                if (n < 1024) {
                    qo[(size_t)row * H_ + n] = v;
                } else if (n < 2048) {
                    ko[(size_t)row * H_ + (n - 1024)] = v;
                } else {
                    int b = row >> 11, t = row & (T_ - 1);
                    vo[((size_t)b * H_ + (n - 2048)) * T_ + t] = v;
                }
            }
        }
    }
}

// ---------------- flash attention v2 ----------------
// 64 q-rows x 128 s-cols per iteration; 512 threads (8 waves); 1 block/CU.
// Q staged once in LDS (swizzled). Scores fp32 in LDS (granule-swizzled);
// P (bf16) + a_s alias the score buffer behind a read barrier. 160 KiB exactly.
#define INF __builtin_inff()
__global__ __launch_bounds__(512, 2) void attn(const u16* __restrict__ qb,
                                               const u16* __restrict__ kb,
                                               const u16* __restrict__ vtb,
                                               float* __restrict__ out) {
    const int b = blockIdx.y;
    const int t0 = ((int)gridDim.x - 1 - (int)blockIdx.x) * 64;
    const int tid = threadIdx.x;
    const int w = tid >> 6, lane = tid & 63, quad = lane >> 4, l16 = lane & 15;
    const int srow = tid >> 3, sg = tid & 7;   // softmax: 64 rows x 8 threads

    __shared__ u16 Qs[64 * 1024];     // 131072 B
    __shared__ float Ssm[64 * 128];   // 32768 B  -> total 163840 = 160 KiB

    u16* P = (u16*)Ssm;                             // bf16 [64][136] = 17408 B
    float* a_s = (float*)((char*)Ssm + 64 * 136 * 2);  // 256 B at +17408

    const u16* qB = qb + (size_t)b * T_ * H_;
    const u16* kB = kb + (size_t)b * T_ * H_;
    const u16* vB = vtb + (size_t)b * H_ * T_;
    const float scale = 0.03125f;   // E^-0.5

    // stage Q rows [t0, t0+64) into LDS, chunk-XOR swizzled
#pragma unroll
    for (int i = 0; i < 16; i++) {
        int s = i * 512 + tid;           // 0..8191 16B-chunks
        int row = s >> 7, c2 = s & 127;
        int cc = c2 ^ (row & 7);
        gload_lds16(qB + (size_t)(t0 + row) * H_ + cc * 8, &Qs[s * 8]);
    }

    float m_r = -INF, l_r = 0.f;
    f32x4 o[32] = {};   // o[mt*8+ht], wave w owns H cols [w*128, w*128+128)

    __syncthreads();   // Q staged

    for (int s0 = 0; s0 <= t0 + 63; s0 += 128) {
        // ---- phase 1: scores. wave w: col = s0 + w*16 + l16, all 64 rows, 4-way ILP
        f32x4 sc[4] = {};
        {
            const u16* kp = kB + (size_t)(s0 + w * 16 + l16) * H_ + quad * 8;
#pragma unroll 2
            for (int kk = 0; kk < H_; kk += 32) {
                bf16x8 kf = load_frag(kp + kk);
                int kc8 = (kk >> 3) + quad;
#pragma unroll
                for (int mt = 0; mt < 4; mt++) {
                    int row = mt * 16 + l16;
                    int slot = row * 128 + (kc8 ^ (row & 7));
                    bf16x8 af = load_frag(&Qs[slot * 8]);
                    sc[mt] = __builtin_amdgcn_mfma_f32_16x16x32_bf16(af, kf, sc[mt], 0, 0, 0);
                }
            }
        }
        __syncthreads();   // B3': prev iteration's P/a_s reads complete
        {
            int col = w * 16 + l16;
            int g = col >> 2, cl = col & 3;
#pragma unroll
            for (int mt = 0; mt < 4; mt++) {
#pragma unroll
                for (int r = 0; r < 4; r++) {
                    int row = mt * 16 + quad * 4 + r;
                    int g2 = g ^ (row & 7);
                    Ssm[row * 128 + g2 * 4 + cl] =
                        (s0 + col <= t0 + row) ? sc[mt][r] * scale : -INF;
                }
            }
        }
        __syncthreads();   // B1: scores visible

        // ---- phase 2: online softmax (row srow, cols sg*16..+16)
        float vv[16];
#pragma unroll
        for (int i4 = 0; i4 < 4; i4++) {
            int g2 = (sg * 4 + i4) ^ (srow & 7);
            f32x4 t = *(const f32x4*)&Ssm[srow * 128 + g2 * 4];
            vv[i4 * 4 + 0] = t[0]; vv[i4 * 4 + 1] = t[1];
            vv[i4 * 4 + 2] = t[2]; vv[i4 * 4 + 3] = t[3];
        }
        float rmax = vv[0];
#pragma unroll
        for (int i = 1; i < 16; i++) rmax = fmaxf(rmax, vv[i]);
#pragma unroll
        for (int off = 4; off >= 1; off >>= 1) rmax = fmaxf(rmax, __shfl_xor(rmax, off, 64));
        float mn = fmaxf(m_r, rmax);
        float alpha = __expf(m_r - mn);   // m_r=-inf (first iter) -> 0
        float rsum = 0.f;
        u16x8 pl, ph;
#pragma unroll
        for (int i = 0; i < 8; i++) {
            float p = __expf(vv[i] - mn);
            rsum += p; pl[i] = f2bf(p);
        }
#pragma unroll
        for (int i = 0; i < 8; i++) {
            float p = __expf(vv[8 + i] - mn);
            rsum += p; ph[i] = f2bf(p);
        }
#pragma unroll
        for (int off = 4; off >= 1; off >>= 1) rsum += __shfl_xor(rsum, off, 64);
        l_r = l_r * alpha + rsum;
        m_r = mn;
        __syncthreads();   // B1.5: all score reads done before P overwrites Ssm
        *(u16x8*)&P[srow * 136 + sg * 16] = pl;
        *(u16x8*)&P[srow * 136 + sg * 16 + 8] = ph;
        if (sg == 0) a_s[srow] = alpha;
        __syncthreads();   // B2: P + a_s visible

        // ---- phase 3: PV. wave w: H cols w*128..+128
        {
#pragma unroll
            for (int mt = 0; mt < 4; mt++) {
#pragma unroll
                for (int r = 0; r < 4; r++) {
                    float al = a_s[mt * 16 + quad * 4 + r];
#pragma unroll
                    for (int ht = 0; ht < 8; ht++) o[mt * 8 + ht][r] *= al;
                }
            }
            const u16* vp = vB + (size_t)(w * 128 + l16) * T_ + s0 + quad * 8;
#pragma unroll
            for (int kc = 0; kc < 4; kc++) {
                bf16x8 pa[4];
#pragma unroll
                for (int mt = 0; mt < 4; mt++)
                    pa[mt] = load_frag(&P[(mt * 16 + l16) * 136 + kc * 32 + quad * 8]);
#pragma unroll
                for (int ht = 0; ht < 8; ht++) {
                    bf16x8 vf = load_frag(vp + (size_t)ht * 16 * T_ + kc * 32);
#pragma unroll
                    for (int mt = 0; mt < 4; mt++)
                        o[mt * 8 + ht] = __builtin_amdgcn_mfma_f32_16x16x32_bf16(
                            pa[mt], vf, o[mt * 8 + ht], 0, 0, 0);
                }
            }
        }
        // no barrier here: next phase-1 compute touches only Qs + globals;
        // B3' protects Ssm before it is overwritten.
    }

    // ---- epilogue: O / l
    __syncthreads();
    if (sg == 0) a_s[srow] = l_r;
    __syncthreads();
    float* ob = out + (size_t)b * T_ * H_;
#pragma unroll
    for (int mt = 0; mt < 4; mt++) {
#pragma unroll
        for (int r = 0; r < 4; r++) {
            float linv = 1.f / a_s[mt * 16 + quad * 4 + r];
            int row = t0 + mt * 16 + quad * 4 + r;
#pragma unroll
            for (int ht = 0; ht < 8; ht++) {
                int col = w * 128 + ht * 16 + l16;
                ob[(size_t)row * H_ + col] = o[mt * 8 + ht][r] * linv;
            }
        }
    }
}

extern "C" void kernel_launch(void* const* d_in, const int* in_sizes, int n_in,
                              void* d_out, int out_size, void* d_ws, size_t ws_size,
                              hipStream_t stream) {
    const float* x  = (const float*)d_in[0];
    const float* Wk = (const float*)d_in[1];
    const float* Wq = (const float*)d_in[2];
    const float* Wv = (const float*)d_in[3];
    float* out = (float*)d_out;

    char* ws = (char*)d_ws;
    const size_t SZ_XB  = (size_t)M_ * E_ * 2;   // 32 MB
    const size_t SZ_W   = (size_t)3 * H_ * E_ * 2; // 6 MB
    const size_t SZ_QKV = (size_t)M_ * H_ * 2;   // 32 MB
    u16* xb   = (u16*)(ws);
    u16* wqkv = (u16*)(ws + SZ_XB);
    u16* qb   = (u16*)(ws + SZ_XB + SZ_W);
    u16* kb   = (u16*)(ws + SZ_XB + SZ_W + SZ_QKV);
    u16* vtb  = (u16*)(ws + SZ_XB + SZ_W + 2 * SZ_QKV);

    castk<<<M_ * E_ / 4 / 256, 256, 0, stream>>>(x, xb, M_ * E_);
    castk<<<H_ * E_ / 4 / 256, 256, 0, stream>>>(Wq, wqkv, H_ * E_);                 // n in [0,1024)
    castk<<<H_ * E_ / 4 / 256, 256, 0, stream>>>(Wk, wqkv + (size_t)H_ * E_, H_ * E_);     // [1024,2048)
    castk<<<H_ * E_ / 4 / 256, 256, 0, stream>>>(Wv, wqkv + (size_t)2 * H_ * E_, H_ * E_); // [2048,3072)

    gemm_qkv<<<dim3(M_ / 128, 3072 / 128), 256, 0, stream>>>(xb, wqkv, qb, kb, vtb);

    attn<<<dim3(T_ / 64, B_), 512, 0, stream>>>(qb, kb, vtb, out);
}